// Round 1
// baseline (406.025 us; speedup 1.0000x reference)
//
#include <hip/hip_runtime.h>

// Problem dims: B=4, T=16, N=128, D=16, H=64, MH=128, T-1=15 steps.

// ---- workspace float offsets ----
#define OFF_A    0        // A_sym: 4*128*128 = 65536
#define OFF_HS   65536    // hs ping-pong: 2 * 65536
#define OFF_HR   196608   // hr ping-pong: 2 * 65536
#define OFF_HID  327680   // hidden: 4*128*64 = 32768
#define OFF_MSE  360448   // 16 floats (accumulator at [0])
#define OFF_BF   360464   // bf16 weight area: 49152 ushorts (24576 floats)

// ---- bf16 (ushort) offsets within bf area ----
#define BW2F 0        // W_msg2 pre-swizzled B-frags: 16 frags * 64 lanes * 8 = 8192
#define BWIR 8192
#define BWII 9216
#define BWIN 10240
#define BWHR 11264
#define BWHI 15360
#define BWHH 19456
#define BWO1 23552
#define BWO2 27648
#define BWO3 31744
#define BW1S 32768    // W1s then W1r contiguous: 16384 total

#define INIT_TOTAL 278544

typedef __attribute__((ext_vector_type(8))) __bf16 bf16x8;
typedef __attribute__((ext_vector_type(4))) float f32x4;

union frag_u { bf16x8 v; unsigned short s[8]; int4 q; };

__device__ __forceinline__ unsigned short f2b(float x) {
  unsigned int u = __float_as_uint(x);
  u += 0x7fffu + ((u >> 16) & 1u);      // RNE round to bf16
  return (unsigned short)(u >> 16);
}
__device__ __forceinline__ float b2f(unsigned short u) {
  return __uint_as_float(((unsigned int)u) << 16);
}
__device__ __forceinline__ float fast_tanh(float x) {
  // tanh(x) = 1 - 2/(exp2(x*2/ln2)+1); saturates correctly at +-inf
  float e = __builtin_amdgcn_exp2f(x * 2.8853900817779268f);
  return 1.0f - 2.0f * __builtin_amdgcn_rcpf(e + 1.0f);
}
__device__ __forceinline__ float fast_sigmoid(float x) {
  float e = __builtin_amdgcn_exp2f(x * -1.4426950408889634f);
  return __builtin_amdgcn_rcpf(1.0f + e);
}

// ---------------- init: A_sym, hs0/hr0/hidden0/mse0, bf16 weight copies ----------------
__global__ void init_kernel(const float* __restrict__ A, const float* __restrict__ b_msg1,
                            const float* __restrict__ W_msg2,
                            const float* __restrict__ W_ir, const float* __restrict__ W_ii,
                            const float* __restrict__ W_in,
                            const float* __restrict__ W_hr, const float* __restrict__ W_hi,
                            const float* __restrict__ W_hh,
                            const float* __restrict__ W_o1, const float* __restrict__ W_o2,
                            const float* __restrict__ W_o3,
                            const float* __restrict__ W_msg1, float* __restrict__ ws) {
  int idx = blockIdx.x * 256 + threadIdx.x;
  unsigned short* bw = (unsigned short*)(ws + OFF_BF);
  if (idx < 65536) {  // A_sym = clip(sym(A)*(1-I),0,1)
    int b = idx >> 14, rem = idx & 16383, i = rem >> 7, jj = rem & 127;
    float a  = A[idx];
    float at = A[(b << 14) + (jj << 7) + i];
    float v = 0.5f * (a + at);
    v = (i == jj) ? 0.0f : v;
    ws[OFF_A + idx] = fminf(fmaxf(v, 0.0f), 1.0f);
    return;
  }
  idx -= 65536;
  if (idx < 65536) { ws[OFF_HS + idx] = 0.0f; return; }         // hs0 = 0 (parity 0)
  idx -= 65536;
  if (idx < 65536) { ws[OFF_HR + idx] = b_msg1[idx & 127]; return; }  // hr0 = b_msg1
  idx -= 65536;
  if (idx < 32768) { ws[OFF_HID + idx] = 0.0f; return; }        // hidden0 = 0
  idx -= 32768;
  if (idx < 16) { ws[OFF_MSE + idx] = 0.0f; return; }           // mse accumulator
  idx -= 16;
  if (idx < 8192) {  // W_msg2 -> B-fragment order: frag f=(kc*4+nt), lane l, elem jj
    int f = idx >> 9, l = (idx >> 3) & 63, jj = idx & 7;
    int kc = f >> 2, nt = f & 3;
    int k = kc * 32 + ((l >> 4) << 3) + jj;
    int n = (nt << 4) + (l & 15);
    bw[BW2F + idx] = f2b(W_msg2[k * 64 + n]);
    return;
  }
  idx -= 8192;
  if (idx < 1024) { bw[BWIR + idx] = f2b(W_ir[idx]); return; }
  idx -= 1024;
  if (idx < 1024) { bw[BWII + idx] = f2b(W_ii[idx]); return; }
  idx -= 1024;
  if (idx < 1024) { bw[BWIN + idx] = f2b(W_in[idx]); return; }
  idx -= 1024;
  if (idx < 4096) { bw[BWHR + idx] = f2b(W_hr[idx]); return; }
  idx -= 4096;
  if (idx < 4096) { bw[BWHI + idx] = f2b(W_hi[idx]); return; }
  idx -= 4096;
  if (idx < 4096) { bw[BWHH + idx] = f2b(W_hh[idx]); return; }
  idx -= 4096;
  if (idx < 4096) { bw[BWO1 + idx] = f2b(W_o1[idx]); return; }
  idx -= 4096;
  if (idx < 4096) { bw[BWO2 + idx] = f2b(W_o2[idx]); return; }
  idx -= 4096;
  if (idx < 1024) { bw[BWO3 + idx] = f2b(W_o3[idx]); return; }
  idx -= 1024;
  if (idx < 16384) { bw[BW1S + idx] = f2b(W_msg1[idx]); return; }  // W1s|W1r contiguous
}

// ---------------- per-step: agg (MFMA) + GRU + output MLP + next hs/hr ----------------
__launch_bounds__(256, 2)
__global__ void step_kernel(const float* __restrict__ X,
                            const float* __restrict__ b_msg1, const float* __restrict__ b_msg2,
                            const float* __restrict__ b_ir, const float* __restrict__ b_ii,
                            const float* __restrict__ b_in,
                            const float* __restrict__ b_o1, const float* __restrict__ b_o2,
                            const float* __restrict__ b_o3,
                            float* __restrict__ ws, float* __restrict__ out, int t) {
  const int tid = threadIdx.x;
  const int bj = blockIdx.x;
  const int b = bj >> 7, j = bj & 127;
  const int par = t & 1;
  const float* hs_cur = ws + OFF_HS + par * 65536;
  const float* hr_cur = ws + OFF_HR + par * 65536;
  float* hs_nxt = ws + OFF_HS + (par ^ 1) * 65536;
  float* hr_nxt = ws + OFF_HR + (par ^ 1) * 65536;
  const unsigned short* bw = (const unsigned short*)(ws + OFF_BF);

  __shared__ __align__(16) float sh_hr[128];
  __shared__ __align__(16) float sh_Ar[128];
  __shared__ float sh_aggw[4][64];
  __shared__ float sh_agg[64];
  __shared__ float sh_xt[16], sh_xn[16];
  __shared__ float sh_hprev[64], sh_hnew[64], sh_p[64];
  __shared__ float sh_red[16];

  if (tid < 128) {
    sh_hr[tid] = hr_cur[(((b << 7) + j) << 7) + tid];
    sh_Ar[tid] = ws[OFF_A + (b << 14) + (j << 7) + tid];  // A_sym row j == col j (symmetric)
  } else {
    int q = tid - 128;
    if (q < 64) sh_hprev[q] = ws[OFF_HID + (((b << 7) + j) << 6) + q];
    else if (q < 80) {
      int d = q - 64;
      sh_xt[d] = X[((((b << 4) + t) << 11)) + (j << 4) + d];
      sh_xn[d] = X[((((b << 4) + t + 1) << 11)) + (j << 4) + d];
    }
  }
  __syncthreads();

  // ---------- phase 2: agg[b,j,h] = sum_i A[i,j] * tanh(tanh(hs_i+hr_j) @ W2 + b2) ----------
  const int wave = tid >> 6, lane = tid & 63;

  frag_u Bf[16];
  const int4* bw2 = (const int4*)bw;  // BW2F == 0; 16B per (frag,lane)
#pragma unroll
  for (int f = 0; f < 16; ++f) Bf[f].q = bw2[f * 64 + lane];

  float b2v[4];
#pragma unroll
  for (int nt = 0; nt < 4; ++nt) b2v[nt] = b_msg2[nt * 16 + (lane & 15)];

  float part[4] = {0.f, 0.f, 0.f, 0.f};
  const int k0 = (lane >> 4) << 3;

#pragma unroll
  for (int c = 0; c < 2; ++c) {
    const int ibase = ((wave << 1) + c) << 4;
    const int irow = ibase + (lane & 15);
    const float* hsrow = hs_cur + (((b << 7) + irow) << 7);

    f32x4 acc[4];
#pragma unroll
    for (int nt = 0; nt < 4; ++nt) acc[nt] = (f32x4){0.f, 0.f, 0.f, 0.f};

#pragma unroll
    for (int kc = 0; kc < 4; ++kc) {
      const int kk = kc * 32 + k0;
      float4 a0 = *(const float4*)(hsrow + kk);
      float4 a1 = *(const float4*)(hsrow + kk + 4);
      float4 h0 = *(const float4*)(sh_hr + kk);
      float4 h1 = *(const float4*)(sh_hr + kk + 4);
      frag_u Af;
      Af.s[0] = f2b(fast_tanh(a0.x + h0.x));
      Af.s[1] = f2b(fast_tanh(a0.y + h0.y));
      Af.s[2] = f2b(fast_tanh(a0.z + h0.z));
      Af.s[3] = f2b(fast_tanh(a0.w + h0.w));
      Af.s[4] = f2b(fast_tanh(a1.x + h1.x));
      Af.s[5] = f2b(fast_tanh(a1.y + h1.y));
      Af.s[6] = f2b(fast_tanh(a1.z + h1.z));
      Af.s[7] = f2b(fast_tanh(a1.w + h1.w));
#pragma unroll
      for (int nt = 0; nt < 4; ++nt)
        acc[nt] = __builtin_amdgcn_mfma_f32_16x16x32_bf16(Af.v, Bf[kc * 4 + nt].v, acc[nt], 0, 0, 0);
    }
    // epilogue: rows of reg r are i = ibase + (lane>>4)*4 + r ; col = nt*16 + (lane&15)
    float4 aw = *(const float4*)(sh_Ar + ibase + ((lane >> 4) << 2));
#pragma unroll
    for (int r = 0; r < 4; ++r) {
      float wv = (r == 0) ? aw.x : (r == 1) ? aw.y : (r == 2) ? aw.z : aw.w;
#pragma unroll
      for (int nt = 0; nt < 4; ++nt)
        part[nt] += wv * fast_tanh(acc[nt][r] + b2v[nt]);
    }
  }
#pragma unroll
  for (int nt = 0; nt < 4; ++nt) {
    part[nt] += __shfl_xor(part[nt], 16);
    part[nt] += __shfl_xor(part[nt], 32);
  }
  if (lane < 16) {
#pragma unroll
    for (int nt = 0; nt < 4; ++nt) sh_aggw[wave][nt * 16 + lane] = part[nt];
  }
  __syncthreads();
  if (tid < 64)
    sh_agg[tid] = sh_aggw[0][tid] + sh_aggw[1][tid] + sh_aggw[2][tid] + sh_aggw[3][tid];
  __syncthreads();

  // ---------- phase 3a: gates + hidden update (row j) ----------
  if (tid < 64) {
    const int h = tid;
    float pre_r = b_ir[h], pre_i = b_ii[h], pre_n = b_in[h], hh = 0.f;
#pragma unroll
    for (int d = 0; d < 16; ++d) {
      float xv = sh_xt[d];
      pre_r += xv * b2f(bw[BWIR + d * 64 + h]);
      pre_i += xv * b2f(bw[BWII + d * 64 + h]);
      pre_n += xv * b2f(bw[BWIN + d * 64 + h]);
    }
    for (int k = 0; k < 64; ++k) {
      float av = sh_agg[k];
      pre_r += av * b2f(bw[BWHR + k * 64 + h]);
      pre_i += av * b2f(bw[BWHI + k * 64 + h]);
      hh    += av * b2f(bw[BWHH + k * 64 + h]);
    }
    float r  = fast_sigmoid(pre_r);
    float ig = fast_sigmoid(pre_i);
    float n  = fast_tanh(pre_n + r * hh);
    float hnew = (1.f - ig) * n + ig * sh_hprev[h];
    sh_hnew[h] = hnew;
    ws[OFF_HID + (((b << 7) + j) << 6) + h] = hnew;
  }
  __syncthreads();

  // ---------- phase 3b: p1 (threads 0..63)  ||  next hs/hr (threads 64..191) ----------
  if (tid < 64) {
    const int h = tid;
    float s = b_o1[h];
    for (int k = 0; k < 64; ++k) s += sh_hnew[k] * b2f(bw[BWO1 + k * 64 + h]);
    sh_p[h] = fmaxf(s, 0.f);
  } else if (tid < 192) {
    const int m = tid - 64;
    float s1 = 0.f, s2 = b_msg1[m];
    for (int h = 0; h < 64; ++h) {
      float hv = sh_hnew[h];
      s1 += hv * b2f(bw[BW1S + h * 128 + m]);          // W1s
      s2 += hv * b2f(bw[BW1S + 8192 + h * 128 + m]);   // W1r
    }
    hs_nxt[(((b << 7) + j) << 7) + m] = s1;
    hr_nxt[(((b << 7) + j) << 7) + m] = s2;
  }
  __syncthreads();

  // ---------- phase 3c: p2 (reuse sh_hprev as p2) ----------
  if (tid < 64) {
    const int h = tid;
    float s = b_o2[h];
    for (int k = 0; k < 64; ++k) s += sh_p[k] * b2f(bw[BWO2 + k * 64 + h]);
    sh_hprev[h] = fmaxf(s, 0.f);
  }
  __syncthreads();

  // ---------- phase 3d: pred + mse ----------
  if (tid < 16) {
    const int d = tid;
    float s = b_o3[d];
    for (int k = 0; k < 64; ++k) s += sh_hprev[k] * b2f(bw[BWO3 + k * 16 + d]);
    float pred = sh_xt[d] + s;
    out[(((b * 15) + t) * 128 + j) * 16 + d] = pred;
    float diff = sh_xn[d] - pred;
    sh_red[d] = diff * diff;
  }
  __syncthreads();
  if (tid == 0) {
    float s = 0.f;
#pragma unroll
    for (int d = 0; d < 16; ++d) s += sh_red[d];
    atomicAdd(ws + OFF_MSE, s);
  }
}

// ---------------- finalize: loglik ----------------
__global__ void final_kernel(const float* __restrict__ log_sigma, const float* __restrict__ ws,
                             float* __restrict__ out) {
  if (threadIdx.x == 0 && blockIdx.x == 0) {
    float sigma = expf(log_sigma[0]);
    float mse = ws[OFF_MSE];
    float cst = 8192.0f * logf(sigma * sqrtf(6.2831853071795864f));  // N*D*B = 8192
    out[122880] = -(mse / (2.0f * sigma * sigma) + 15.0f * cst);
  }
}

extern "C" void kernel_launch(void* const* d_in, const int* in_sizes, int n_in,
                              void* d_out, int out_size, void* d_ws, size_t ws_size,
                              hipStream_t stream) {
  (void)in_sizes; (void)n_in; (void)out_size; (void)ws_size;
  const float* A      = (const float*)d_in[0];
  const float* X      = (const float*)d_in[1];
  const float* W_msg1 = (const float*)d_in[2];
  const float* b_msg1 = (const float*)d_in[3];
  const float* W_msg2 = (const float*)d_in[4];
  const float* b_msg2 = (const float*)d_in[5];
  const float* W_ir   = (const float*)d_in[6];
  const float* b_ir   = (const float*)d_in[7];
  const float* W_ii   = (const float*)d_in[8];
  const float* b_ii   = (const float*)d_in[9];
  const float* W_in   = (const float*)d_in[10];
  const float* b_in   = (const float*)d_in[11];
  const float* W_hr   = (const float*)d_in[12];
  const float* W_hi   = (const float*)d_in[13];
  const float* W_hh   = (const float*)d_in[14];
  const float* W_o1   = (const float*)d_in[15];
  const float* b_o1   = (const float*)d_in[16];
  const float* W_o2   = (const float*)d_in[17];
  const float* b_o2   = (const float*)d_in[18];
  const float* W_o3   = (const float*)d_in[19];
  const float* b_o3   = (const float*)d_in[20];
  const float* log_sigma = (const float*)d_in[21];
  float* ws  = (float*)d_ws;
  float* out = (float*)d_out;

  init_kernel<<<(INIT_TOTAL + 255) / 256, 256, 0, stream>>>(
      A, b_msg1, W_msg2, W_ir, W_ii, W_in, W_hr, W_hi, W_hh, W_o1, W_o2, W_o3, W_msg1, ws);
  for (int t = 0; t < 15; ++t)
    step_kernel<<<512, 256, 0, stream>>>(X, b_msg1, b_msg2, b_ir, b_ii, b_in,
                                         b_o1, b_o2, b_o3, ws, out, t);
  final_kernel<<<1, 64, 0, stream>>>(log_sigma, ws, out);
}